// Round 29
// baseline (93.612 us; speedup 1.0000x reference)
//
#include <hip/hip_runtime.h>

typedef _Float16 f16;
typedef _Float16 f16x4 __attribute__((ext_vector_type(4)));
typedef _Float16 f16x8 __attribute__((ext_vector_type(8)));
typedef float f32x4 __attribute__((ext_vector_type(4)));

#define MFMA16(a, b, c) __builtin_amdgcn_mfma_f32_16x16x32_f16(a, b, c, 0, 0, 0)

constexpr int T = 2048;
constexpr int E = 1024;
constexpr int H = 16;
constexpr int D = 64;
constexpr int WIN = 256;
#define NEGF (-1e30f)
#define L2E 1.4426950408889634f

// async global->LDS, 16B per lane; LDS base must be wave-uniform (HW: base + lane*16)
__device__ __forceinline__ void gload16(const f16* g, f16* l) {
  __builtin_amdgcn_global_load_lds(
      (__attribute__((address_space(1))) void*)(void*)g,
      (__attribute__((address_space(3))) void*)(void*)l, 16, 0, 0);
}

// ---------------- merged prep: cast x (f32->f16) + transpose weights ----------------
__global__ __launch_bounds__(256) void prep_kernel(
    const float* __restrict__ x, f16* __restrict__ xb,
    const float* __restrict__ w0, const float* __restrict__ w1,
    const float* __restrict__ w2, const float* __restrict__ w3,
    f16* __restrict__ o0, f16* __restrict__ o1, f16* __restrict__ o2,
    f16* __restrict__ o3) {
  if (blockIdx.x < 4096) {
    int idx = (blockIdx.x * 256 + threadIdx.x) * 4;
    float4 v = *(const float4*)(x + idx);
    f16x4 o = {(f16)v.x, (f16)v.y, (f16)v.z, (f16)v.w};
    *(f16x4*)(xb + idx) = o;
    return;
  }
  int bid = blockIdx.x - 4096;
  int z = bid >> 8;
  const float* w = z == 0 ? w0 : z == 1 ? w1 : z == 2 ? w2 : w3;
  f16* o = z == 0 ? o0 : z == 1 ? o1 : z == 2 ? o2 : o3;
  __shared__ float tile[64][65];
  int k0 = ((bid >> 4) & 15) * 64, n0 = (bid & 15) * 64;
  int r = threadIdx.x >> 2, cb = (threadIdx.x & 3) * 16;
  const float* src = w + (size_t)(k0 + r) * E + n0 + cb;
#pragma unroll
  for (int j = 0; j < 16; j += 4) {
    float4 v = *(const float4*)(src + j);
    tile[r][cb + j] = v.x;
    tile[r][cb + j + 1] = v.y;
    tile[r][cb + j + 2] = v.z;
    tile[r][cb + j + 3] = v.w;
  }
  __syncthreads();
  f16 tmp[16];
#pragma unroll
  for (int j = 0; j < 16; ++j) tmp[j] = (f16)tile[cb + j][r];
  f16* dst = o + (size_t)(n0 + r) * E + k0 + cb;
  *(f16x8*)dst = *(f16x8*)&tmp[0];
  *(f16x8*)(dst + 8) = *(f16x8*)&tmp[8];
}

// ---------------- QKV GEMM: 64x128 tiles -> 1536 blocks, 3/CU (R25/R27) -------
// BN=128 so each wave spans one full 64-col head chunk (fused RMSNorm
// requirement). LDS 48KB, 4 waves (2m x 2n): wave owns 32x64 out, acc[2][4].
// z=0/1 -> fused RMSNorm epilogue (q folds 0.125), z=2 -> V-transpose.
__global__ __launch_bounds__(256) void qkv_gemm_kernel(
    const f16* __restrict__ A, const f16* __restrict__ B0,
    const f16* __restrict__ B1, const f16* __restrict__ B2,
    const float* __restrict__ c0, const float* __restrict__ c1,
    const float* __restrict__ c2, const float* __restrict__ qnw,
    const float* __restrict__ knw, f16* __restrict__ oq, f16* __restrict__ ok,
    f16* __restrict__ Vt, int M, int N, int K) {
  int z = blockIdx.z;
  const f16* Bt = z == 0 ? B0 : z == 1 ? B1 : B2;
  const float* bias = z == 0 ? c0 : z == 1 ? c1 : c2;

  __shared__ f16 lA[2][4096];  // 64x64
  __shared__ f16 lB[2][8192];  // 128x64

  int sw = ((blockIdx.x & 7) << 6) + (blockIdx.x >> 3);
  int m0 = (sw >> 3) << 6, n0 = (sw & 7) << 7;

  int tid = threadIdx.x;
  int wid = tid >> 6, lane = tid & 63;
  int wm = wid >> 1, wn = wid & 1;
  int lr = lane & 15, lg = lane >> 4;

  f32x4 zero = {0.f, 0.f, 0.f, 0.f};
  f32x4 acc[2][4];
  for (int a = 0; a < 2; ++a)
    for (int b = 0; b < 4; ++b) acc[a][b] = zero;

  int srow = lane >> 3;
  int scol = (lane & 7) << 3;

  auto stage = [&](int buf, int k0) {
#pragma unroll
    for (int p = 0; p < 2; ++p) {  // 8 calls cover 64x64 A tile
      int cc = (wid << 1) + p;
      int row = (cc << 3) + srow;
      int gc = scol ^ ((row & 7) << 3);
      gload16(A + (size_t)(m0 + row) * K + k0 + gc, &lA[buf][cc << 9]);
    }
#pragma unroll
    for (int p = 0; p < 4; ++p) {  // 16 calls cover 128x64 B tile
      int cc = (wid << 2) + p;
      int row = (cc << 3) + srow;
      int gc = scol ^ ((row & 7) << 3);
      gload16(Bt + (size_t)(n0 + row) * K + k0 + gc, &lB[buf][cc << 9]);
    }
  };

  int nit = K >> 6;
  stage(0, 0);
  __syncthreads();
  int cur = 0;
  for (int t = 0; t < nit; ++t) {
    if (t + 1 < nit) stage(cur ^ 1, (t + 1) << 6);
#pragma unroll
    for (int kk = 0; kk < 2; ++kk) {
      int kc = kk * 32 + (lg << 3);
      f16x8 af[2], bf[4];
#pragma unroll
      for (int mt = 0; mt < 2; ++mt) {
        int row = wm * 32 + mt * 16 + lr;
        af[mt] = *(const f16x8*)&lA[cur][((row << 6) + kc) ^ ((row & 7) << 3)];
      }
#pragma unroll
      for (int nt = 0; nt < 4; ++nt) {
        int row = wn * 64 + nt * 16 + lr;
        bf[nt] = *(const f16x8*)&lB[cur][((row << 6) + kc) ^ ((row & 7) << 3)];
      }
#pragma unroll
      for (int mt = 0; mt < 2; ++mt)
#pragma unroll
        for (int nt = 0; nt < 4; ++nt)
          acc[mt][nt] = MFMA16(af[mt], bf[nt], acc[mt][nt]);
    }
    if (t + 1 < nit) {
      __syncthreads();
      cur ^= 1;
    }
  }

  if (z < 2) {
    const float* nw = z == 0 ? qnw : knw;
    f16* o = z == 0 ? oq : ok;
    const float eps = 1.1920929e-7f;
    const float osc = z == 0 ? 0.125f : 1.0f;
    float wv_[4];
#pragma unroll
    for (int nt = 0; nt < 4; ++nt) wv_[nt] = nw[nt * 16 + lr] * osc;
#pragma unroll
    for (int mt = 0; mt < 2; ++mt) {
      float vbuf[4][4];
      float ss[4] = {0.f, 0.f, 0.f, 0.f};
#pragma unroll
      for (int nt = 0; nt < 4; ++nt) {
        float bv = bias[n0 + wn * 64 + nt * 16 + lr];
#pragma unroll
        for (int i = 0; i < 4; ++i) {
          float v = acc[mt][nt][i] + bv;
          vbuf[nt][i] = v;
          ss[i] += v * v;
        }
      }
      float rr[4];
#pragma unroll
      for (int i = 0; i < 4; ++i) {
        ss[i] += __shfl_xor(ss[i], 1);
        ss[i] += __shfl_xor(ss[i], 2);
        ss[i] += __shfl_xor(ss[i], 4);
        ss[i] += __shfl_xor(ss[i], 8);
        rr[i] = rsqrtf(ss[i] * (1.0f / 64.0f) + eps);
      }
      int row = m0 + wm * 32 + mt * 16 + (lg << 2);
#pragma unroll
      for (int nt = 0; nt < 4; ++nt) {
        int col = n0 + wn * 64 + nt * 16 + lr;
#pragma unroll
        for (int i = 0; i < 4; ++i)
          o[(size_t)(row + i) * N + col] = (f16)(vbuf[nt][i] * rr[i] * wv_[nt]);
      }
    }
  } else {
#pragma unroll
    for (int mt = 0; mt < 2; ++mt) {
      int row = m0 + wm * 32 + mt * 16 + (lg << 2);
      int b = row >> 11;
      int t = row & (T - 1);
#pragma unroll
      for (int nt = 0; nt < 4; ++nt) {
        int col = n0 + wn * 64 + nt * 16 + lr;
        float bv = bias[col];
        int h = col >> 6, d = col & 63;
        f16x4 pk = {(f16)(acc[mt][nt][0] + bv), (f16)(acc[mt][nt][1] + bv),
                    (f16)(acc[mt][nt][2] + bv), (f16)(acc[mt][nt][3] + bv)};
        *(f16x4*)&Vt[(((size_t)(b * H + h) * D + d) << 11) + t] = pk;
      }
    }
  }
}

// ---------------- out GEMM: 128x64 tiles -> 512 blocks (R21/R25-measured) -----
__global__ __launch_bounds__(256) void out_gemm_kernel(
    const f16* __restrict__ A, const f16* __restrict__ Bt,
    const float* __restrict__ bias, float* __restrict__ out, int M, int N,
    int K) {
  __shared__ f16 lA[2][8192];  // 128x64
  __shared__ f16 lB[2][4096];  // 64x64

  int sw = ((blockIdx.x & 7) << 6) + (blockIdx.x >> 3);
  int m0 = (sw >> 4) << 7, n0 = (sw & 15) << 6;

  int tid = threadIdx.x;
  int wid = tid >> 6, lane = tid & 63;
  int wm = wid >> 1, wn = wid & 1;
  int lr = lane & 15, lg = lane >> 4;

  f32x4 zero = {0.f, 0.f, 0.f, 0.f};
  f32x4 acc[4][2];
  for (int a = 0; a < 4; ++a)
    for (int b = 0; b < 2; ++b) acc[a][b] = zero;

  int srow = lane >> 3;
  int scol = (lane & 7) << 3;

  auto stage = [&](int buf, int k0) {
#pragma unroll
    for (int p = 0; p < 4; ++p) {
      int cc = (wid << 2) + p;
      int row = (cc << 3) + srow;
      int gc = scol ^ ((row & 7) << 3);
      gload16(A + (size_t)(m0 + row) * K + k0 + gc, &lA[buf][cc << 9]);
    }
#pragma unroll
    for (int p = 0; p < 2; ++p) {
      int cc = (wid << 1) + p;
      int row = (cc << 3) + srow;
      int gc = scol ^ ((row & 7) << 3);
      gload16(Bt + (size_t)(n0 + row) * K + k0 + gc, &lB[buf][cc << 9]);
    }
  };

  int nit = K >> 6;
  stage(0, 0);
  __syncthreads();
  int cur = 0;
  for (int t = 0; t < nit; ++t) {
    if (t + 1 < nit) stage(cur ^ 1, (t + 1) << 6);
#pragma unroll
    for (int kk = 0; kk < 2; ++kk) {
      int kc = kk * 32 + (lg << 3);
      f16x8 af[4], bf[2];
#pragma unroll
      for (int mt = 0; mt < 4; ++mt) {
        int row = wm * 64 + mt * 16 + lr;
        af[mt] = *(const f16x8*)&lA[cur][((row << 6) + kc) ^ ((row & 7) << 3)];
      }
#pragma unroll
      for (int nt = 0; nt < 2; ++nt) {
        int row = wn * 32 + nt * 16 + lr;
        bf[nt] = *(const f16x8*)&lB[cur][((row << 6) + kc) ^ ((row & 7) << 3)];
      }
#pragma unroll
      for (int mt = 0; mt < 4; ++mt)
#pragma unroll
        for (int nt = 0; nt < 2; ++nt)
          acc[mt][nt] = MFMA16(af[mt], bf[nt], acc[mt][nt]);
    }
    if (t + 1 < nit) {
      __syncthreads();
      cur ^= 1;
    }
  }

#pragma unroll
  for (int mt = 0; mt < 4; ++mt) {
#pragma unroll
    for (int nt = 0; nt < 2; ++nt) {
      int row = m0 + wm * 64 + mt * 16 + (lg << 2);
      int col = n0 + wn * 32 + nt * 16 + lr;
      float bv = bias[col];
#pragma unroll
      for (int i = 0; i < 4; ++i)
        out[(size_t)(row + i) * N + col] = acc[mt][nt][i] + bv;
    }
  }
}

// ---------------- sliding-window flash attention (R24/R27 + T13 THR=8) --------
// T13 defer-max: skip rescale unless some row's max grew by >8; P then
// bounded by 2^8 (f16-safe), scaling stays consistent at exp2(-m_old).
// First live tile always triggers (tm >> NEGF+8) -> fac=0 heal preserved.
__global__ __launch_bounds__(256) void attn_kernel(const f16* __restrict__ qn,
                                                   const f16* __restrict__ kn,
                                                   const f16* __restrict__ Vt,
                                                   f16* __restrict__ aout) {
  int sw = ((blockIdx.x & 7) << 7) + (blockIdx.x >> 3);
  int q0 = (sw & 31) << 6;
  int bh = sw >> 5;
  int b = bh >> 4, h = bh & 15;
  int tid = threadIdx.x;
  int w = tid >> 6, lane = tid & 63;
  int lr = lane & 15, lg = lane >> 4;

  __shared__ f16 lK[2][4096];
  __shared__ f16 lV[2][4096];
  __shared__ f16 lP[4096];

  const f16* Qb = qn + (size_t)(b * T + q0 + w * 16 + lr) * E + h * 64 + (lg << 3);
  f16x8 qf0 = *(const f16x8*)Qb;
  f16x8 qf1 = *(const f16x8*)(Qb + 32);

  f32x4 zero = {0.f, 0.f, 0.f, 0.f};
  f32x4 acc[4] = {zero, zero, zero, zero};
  float m[4] = {NEGF, NEGF, NEGF, NEGF};
  float l[4] = {0.f, 0.f, 0.f, 0.f};

  int mi = q0 >> 6;
  int kts = mi - 4 < 0 ? 0 : mi - 4;

  const f16* Kbase = kn + (size_t)b * T * E + h * 64;
  const f16* Vbase = Vt + (size_t)bh * D * T;

  int srow = lane >> 3;
  int scol = (lane & 7) << 3;

  auto stageKV = [&](int buf, int kt) {
    int k0 = kt << 6;
#pragma unroll
    for (int p = 0; p < 2; ++p) {
      int cc = (w << 1) + p;
      int row = (cc << 3) + srow;
      int gc = scol ^ ((row & 7) << 3);
      gload16(Kbase + (size_t)(k0 + row) * E + gc, &lK[buf][cc << 9]);
      gload16(Vbase + (size_t)row * T + k0 + gc, &lV[buf][cc << 9]);
    }
  };

  stageKV(0, kts);
  __syncthreads();
  int cur = 0;

  for (int kt = kts; kt <= mi; ++kt) {
    if (kt < mi) stageKV(cur ^ 1, kt + 1);
    int k0 = kt << 6;

    f32x4 s[4];
#pragma unroll
    for (int ct = 0; ct < 4; ++ct) s[ct] = zero;
    __builtin_amdgcn_s_setprio(1);
#pragma unroll
    for (int kk = 0; kk < 2; ++kk) {
      int kc = kk * 32 + (lg << 3);
#pragma unroll
      for (int ct = 0; ct < 4; ++ct) {
        int row = ct * 16 + lr;
        f16x8 bf = *(const f16x8*)&lK[cur][((row << 6) + kc) ^ ((row & 7) << 3)];
        s[ct] = MFMA16(kk == 0 ? qf0 : qf1, bf, s[ct]);
      }
    }
    __builtin_amdgcn_s_setprio(0);

    float tm[4] = {NEGF, NEGF, NEGF, NEGF};
    int rowg0 = q0 + w * 16 + (lg << 2);
    bool needmask = (kt == mi) || (mi >= 4 && kt == kts);
    if (needmask) {
#pragma unroll
      for (int ct = 0; ct < 4; ++ct) {
        int col = k0 + ct * 16 + lr;
#pragma unroll
        for (int i = 0; i < 4; ++i) {
          int rowg = rowg0 + i;
          float v = s[ct][i];
          if (col > rowg || rowg - col >= WIN) v = NEGF;
          s[ct][i] = v;
          tm[i] = fmaxf(tm[i], v);
        }
      }
    } else {
#pragma unroll
      for (int ct = 0; ct < 4; ++ct)
#pragma unroll
        for (int i = 0; i < 4; ++i) tm[i] = fmaxf(tm[i], s[ct][i]);
    }
#pragma unroll
    for (int i = 0; i < 4; ++i) {
      tm[i] = fmaxf(tm[i], __shfl_xor(tm[i], 1));
      tm[i] = fmaxf(tm[i], __shfl_xor(tm[i], 2));
      tm[i] = fmaxf(tm[i], __shfl_xor(tm[i], 4));
      tm[i] = fmaxf(tm[i], __shfl_xor(tm[i], 8));
    }
    // T13 defer-max (THR=8): rescale only when a row's max grew by >8.
    bool up = (tm[0] > m[0] + 8.0f) || (tm[1] > m[1] + 8.0f) ||
              (tm[2] > m[2] + 8.0f) || (tm[3] > m[3] + 8.0f);
    if (__any(up)) {
      float fac[4];
#pragma unroll
      for (int i = 0; i < 4; ++i) {
        float mn = fmaxf(m[i], tm[i]);
        fac[i] = exp2f((m[i] - mn) * L2E);
        m[i] = mn;
        l[i] *= fac[i];
      }
#pragma unroll
      for (int dt = 0; dt < 4; ++dt)
#pragma unroll
        for (int i = 0; i < 4; ++i) acc[dt][i] *= fac[i];
    }
    float ps[4] = {0.f, 0.f, 0.f, 0.f};
#pragma unroll
    for (int ct = 0; ct < 4; ++ct)
#pragma unroll
      for (int i = 0; i < 4; ++i) {
        float p = exp2f((s[ct][i] - m[i]) * L2E);
        s[ct][i] = p;
        ps[i] += p;
      }
#pragma unroll
    for (int i = 0; i < 4; ++i) {
      ps[i] += __shfl_xor(ps[i], 1);
      ps[i] += __shfl_xor(ps[i], 2);
      ps[i] += __shfl_xor(ps[i], 4);
      ps[i] += __shfl_xor(ps[i], 8);
      l[i] += ps[i];
    }

#pragma unroll
    for (int ct = 0; ct < 4; ++ct)
#pragma unroll
      for (int i = 0; i < 4; ++i) {
        int qloc = (lg << 2) + i;
        int el = (qloc << 6) + ct * 16 + lr;
        lP[w * 1024 + (el ^ ((qloc & 7) << 3))] = (f16)s[ct][i];
      }

    __builtin_amdgcn_s_setprio(1);
#pragma unroll
    for (int kk = 0; kk < 2; ++kk) {
      int kc = kk * 32 + (lg << 3);
      int ep = w * 1024 + (((lr << 6) + kc) ^ ((lr & 7) << 3));
      f16x8 pf = *(const f16x8*)&lP[ep];
#pragma unroll
      for (int dt = 0; dt < 4; ++dt) {
        int row = dt * 16 + lr;
        f16x8 vf = *(const f16x8*)&lV[cur][((row << 6) + kc) ^ ((row & 7) << 3)];
        acc[dt] = MFMA16(pf, vf, acc[dt]);
      }
    }
    __builtin_amdgcn_s_setprio(0);

    if (kt < mi) {
      __syncthreads();
      cur ^= 1;
    }
  }

#pragma unroll
  for (int i = 0; i < 4; ++i) {
    float inv = 1.0f / l[i];
    int tok = q0 + w * 16 + (lg << 2) + i;
    f16* dst = aout + (size_t)(b * T + tok) * E + h * 64 + lr;
#pragma unroll
    for (int dt = 0; dt < 4; ++dt) dst[dt * 16] = (f16)(acc[dt][i] * inv);
  }
}

// ---------------- launch ----------------
extern "C" void kernel_launch(void* const* d_in, const int* in_sizes, int n_in,
                              void* d_out, int out_size, void* d_ws,
                              size_t ws_size, hipStream_t stream) {
  const float* x = (const float*)d_in[0];
  const float* wq = (const float*)d_in[1];
  const float* bq = (const float*)d_in[2];
  const float* wk = (const float*)d_in[3];
  const float* bk = (const float*)d_in[4];
  const float* wv = (const float*)d_in[5];
  const float* bv = (const float*)d_in[6];
  const float* wo = (const float*)d_in[7];
  const float* bo = (const float*)d_in[8];
  const float* qn_w = (const float*)d_in[9];
  const float* kn_w = (const float*)d_in[10];
  float* out = (float*)d_out;

  char* ws = (char*)d_ws;
  const size_t MB = 1u << 20;
  f16* xb = (f16*)(ws);              // 8 MB
  f16* wqT = (f16*)(ws + 8 * MB);    // 2 MB
  f16* wkT = (f16*)(ws + 10 * MB);   // 2 MB
  f16* wvT = (f16*)(ws + 12 * MB);   // 2 MB
  f16* woT = (f16*)(ws + 14 * MB);   // 2 MB
  f16* qn = (f16*)(ws + 16 * MB);    // 8 MB
  f16* kn = (f16*)(ws + 24 * MB);    // 8 MB
  f16* Vt = (f16*)(ws + 32 * MB);    // 8 MB
  f16* aout = (f16*)(ws + 40 * MB);  // 8 MB

  prep_kernel<<<5120, 256, 0, stream>>>(x, xb, wq, wk, wv, wo, wqT, wkT, wvT,
                                        woT);
  qkv_gemm_kernel<<<dim3(512, 1, 3), 256, 0, stream>>>(
      xb, wqT, wkT, wvT, bq, bk, bv, qn_w, kn_w, qn, kn, Vt, 4096, 1024, 1024);
  attn_kernel<<<1024, 256, 0, stream>>>(qn, kn, Vt, aout);
  out_gemm_kernel<<<512, 256, 0, stream>>>(aout, woT, bo, out, 4096, 1024,
                                           1024);
}

// Round 30
// 93.100 us; speedup vs baseline: 1.0055x; 1.0055x over previous
//
#include <hip/hip_runtime.h>

typedef _Float16 f16;
typedef _Float16 f16x4 __attribute__((ext_vector_type(4)));
typedef _Float16 f16x8 __attribute__((ext_vector_type(8)));
typedef float f32x4 __attribute__((ext_vector_type(4)));

#define MFMA16(a, b, c) __builtin_amdgcn_mfma_f32_16x16x32_f16(a, b, c, 0, 0, 0)

constexpr int T = 2048;
constexpr int E = 1024;
constexpr int H = 16;
constexpr int D = 64;
constexpr int WIN = 256;
#define NEGF (-1e30f)
#define L2E 1.4426950408889634f

// async global->LDS, 16B per lane; LDS base must be wave-uniform (HW: base + lane*16)
__device__ __forceinline__ void gload16(const f16* g, f16* l) {
  __builtin_amdgcn_global_load_lds(
      (__attribute__((address_space(1))) void*)(void*)g,
      (__attribute__((address_space(3))) void*)(void*)l, 16, 0, 0);
}

// ---------------- merged prep: cast x (f32->f16) + transpose weights ----------------
__global__ __launch_bounds__(256) void prep_kernel(
    const float* __restrict__ x, f16* __restrict__ xb,
    const float* __restrict__ w0, const float* __restrict__ w1,
    const float* __restrict__ w2, const float* __restrict__ w3,
    f16* __restrict__ o0, f16* __restrict__ o1, f16* __restrict__ o2,
    f16* __restrict__ o3) {
  if (blockIdx.x < 4096) {
    int idx = (blockIdx.x * 256 + threadIdx.x) * 4;
    float4 v = *(const float4*)(x + idx);
    f16x4 o = {(f16)v.x, (f16)v.y, (f16)v.z, (f16)v.w};
    *(f16x4*)(xb + idx) = o;
    return;
  }
  int bid = blockIdx.x - 4096;
  int z = bid >> 8;
  const float* w = z == 0 ? w0 : z == 1 ? w1 : z == 2 ? w2 : w3;
  f16* o = z == 0 ? o0 : z == 1 ? o1 : z == 2 ? o2 : o3;
  __shared__ float tile[64][65];
  int k0 = ((bid >> 4) & 15) * 64, n0 = (bid & 15) * 64;
  int r = threadIdx.x >> 2, cb = (threadIdx.x & 3) * 16;
  const float* src = w + (size_t)(k0 + r) * E + n0 + cb;
#pragma unroll
  for (int j = 0; j < 16; j += 4) {
    float4 v = *(const float4*)(src + j);
    tile[r][cb + j] = v.x;
    tile[r][cb + j + 1] = v.y;
    tile[r][cb + j + 2] = v.z;
    tile[r][cb + j + 3] = v.w;
  }
  __syncthreads();
  f16 tmp[16];
#pragma unroll
  for (int j = 0; j < 16; ++j) tmp[j] = (f16)tile[cb + j][r];
  f16* dst = o + (size_t)(n0 + r) * E + k0 + cb;
  *(f16x8*)dst = *(f16x8*)&tmp[0];
  *(f16x8*)(dst + 8) = *(f16x8*)&tmp[8];
}

// ---------------- QKV GEMM: 64x128 tiles -> 1536 blocks, 3/CU (R25/R27) -------
// BN=128 so each wave spans one full 64-col head chunk (fused RMSNorm
// requirement). LDS 48KB, 4 waves (2m x 2n): wave owns 32x64 out, acc[2][4].
// z=0/1 -> fused RMSNorm epilogue (q folds 0.125), z=2 -> V-transpose.
__global__ __launch_bounds__(256) void qkv_gemm_kernel(
    const f16* __restrict__ A, const f16* __restrict__ B0,
    const f16* __restrict__ B1, const f16* __restrict__ B2,
    const float* __restrict__ c0, const float* __restrict__ c1,
    const float* __restrict__ c2, const float* __restrict__ qnw,
    const float* __restrict__ knw, f16* __restrict__ oq, f16* __restrict__ ok,
    f16* __restrict__ Vt, int M, int N, int K) {
  int z = blockIdx.z;
  const f16* Bt = z == 0 ? B0 : z == 1 ? B1 : B2;
  const float* bias = z == 0 ? c0 : z == 1 ? c1 : c2;

  __shared__ f16 lA[2][4096];  // 64x64
  __shared__ f16 lB[2][8192];  // 128x64

  int sw = ((blockIdx.x & 7) << 6) + (blockIdx.x >> 3);
  int m0 = (sw >> 3) << 6, n0 = (sw & 7) << 7;

  int tid = threadIdx.x;
  int wid = tid >> 6, lane = tid & 63;
  int wm = wid >> 1, wn = wid & 1;
  int lr = lane & 15, lg = lane >> 4;

  f32x4 zero = {0.f, 0.f, 0.f, 0.f};
  f32x4 acc[2][4];
  for (int a = 0; a < 2; ++a)
    for (int b = 0; b < 4; ++b) acc[a][b] = zero;

  int srow = lane >> 3;
  int scol = (lane & 7) << 3;

  auto stage = [&](int buf, int k0) {
#pragma unroll
    for (int p = 0; p < 2; ++p) {  // 8 calls cover 64x64 A tile
      int cc = (wid << 1) + p;
      int row = (cc << 3) + srow;
      int gc = scol ^ ((row & 7) << 3);
      gload16(A + (size_t)(m0 + row) * K + k0 + gc, &lA[buf][cc << 9]);
    }
#pragma unroll
    for (int p = 0; p < 4; ++p) {  // 16 calls cover 128x64 B tile
      int cc = (wid << 2) + p;
      int row = (cc << 3) + srow;
      int gc = scol ^ ((row & 7) << 3);
      gload16(Bt + (size_t)(n0 + row) * K + k0 + gc, &lB[buf][cc << 9]);
    }
  };

  int nit = K >> 6;
  stage(0, 0);
  __syncthreads();
  int cur = 0;
  for (int t = 0; t < nit; ++t) {
    if (t + 1 < nit) stage(cur ^ 1, (t + 1) << 6);
#pragma unroll
    for (int kk = 0; kk < 2; ++kk) {
      int kc = kk * 32 + (lg << 3);
      f16x8 af[2], bf[4];
#pragma unroll
      for (int mt = 0; mt < 2; ++mt) {
        int row = wm * 32 + mt * 16 + lr;
        af[mt] = *(const f16x8*)&lA[cur][((row << 6) + kc) ^ ((row & 7) << 3)];
      }
#pragma unroll
      for (int nt = 0; nt < 4; ++nt) {
        int row = wn * 64 + nt * 16 + lr;
        bf[nt] = *(const f16x8*)&lB[cur][((row << 6) + kc) ^ ((row & 7) << 3)];
      }
#pragma unroll
      for (int mt = 0; mt < 2; ++mt)
#pragma unroll
        for (int nt = 0; nt < 4; ++nt)
          acc[mt][nt] = MFMA16(af[mt], bf[nt], acc[mt][nt]);
    }
    if (t + 1 < nit) {
      __syncthreads();
      cur ^= 1;
    }
  }

  if (z < 2) {
    const float* nw = z == 0 ? qnw : knw;
    f16* o = z == 0 ? oq : ok;
    const float eps = 1.1920929e-7f;
    const float osc = z == 0 ? 0.125f : 1.0f;
    float wv_[4];
#pragma unroll
    for (int nt = 0; nt < 4; ++nt) wv_[nt] = nw[nt * 16 + lr] * osc;
#pragma unroll
    for (int mt = 0; mt < 2; ++mt) {
      float vbuf[4][4];
      float ss[4] = {0.f, 0.f, 0.f, 0.f};
#pragma unroll
      for (int nt = 0; nt < 4; ++nt) {
        float bv = bias[n0 + wn * 64 + nt * 16 + lr];
#pragma unroll
        for (int i = 0; i < 4; ++i) {
          float v = acc[mt][nt][i] + bv;
          vbuf[nt][i] = v;
          ss[i] += v * v;
        }
      }
      float rr[4];
#pragma unroll
      for (int i = 0; i < 4; ++i) {
        ss[i] += __shfl_xor(ss[i], 1);
        ss[i] += __shfl_xor(ss[i], 2);
        ss[i] += __shfl_xor(ss[i], 4);
        ss[i] += __shfl_xor(ss[i], 8);
        rr[i] = rsqrtf(ss[i] * (1.0f / 64.0f) + eps);
      }
      int row = m0 + wm * 32 + mt * 16 + (lg << 2);
#pragma unroll
      for (int nt = 0; nt < 4; ++nt) {
        int col = n0 + wn * 64 + nt * 16 + lr;
#pragma unroll
        for (int i = 0; i < 4; ++i)
          o[(size_t)(row + i) * N + col] = (f16)(vbuf[nt][i] * rr[i] * wv_[nt]);
      }
    }
  } else {
#pragma unroll
    for (int mt = 0; mt < 2; ++mt) {
      int row = m0 + wm * 32 + mt * 16 + (lg << 2);
      int b = row >> 11;
      int t = row & (T - 1);
#pragma unroll
      for (int nt = 0; nt < 4; ++nt) {
        int col = n0 + wn * 64 + nt * 16 + lr;
        float bv = bias[col];
        int h = col >> 6, d = col & 63;
        f16x4 pk = {(f16)(acc[mt][nt][0] + bv), (f16)(acc[mt][nt][1] + bv),
                    (f16)(acc[mt][nt][2] + bv), (f16)(acc[mt][nt][3] + bv)};
        *(f16x4*)&Vt[(((size_t)(b * H + h) * D + d) << 11) + t] = pk;
      }
    }
  }
}

// ---------------- out GEMM: 128x64 tiles -> 512 blocks (R21/R25-measured) -----
__global__ __launch_bounds__(256) void out_gemm_kernel(
    const f16* __restrict__ A, const f16* __restrict__ Bt,
    const float* __restrict__ bias, float* __restrict__ out, int M, int N,
    int K) {
  __shared__ f16 lA[2][8192];  // 128x64
  __shared__ f16 lB[2][4096];  // 64x64

  int sw = ((blockIdx.x & 7) << 6) + (blockIdx.x >> 3);
  int m0 = (sw >> 4) << 7, n0 = (sw & 15) << 6;

  int tid = threadIdx.x;
  int wid = tid >> 6, lane = tid & 63;
  int wm = wid >> 1, wn = wid & 1;
  int lr = lane & 15, lg = lane >> 4;

  f32x4 zero = {0.f, 0.f, 0.f, 0.f};
  f32x4 acc[4][2];
  for (int a = 0; a < 4; ++a)
    for (int b = 0; b < 2; ++b) acc[a][b] = zero;

  int srow = lane >> 3;
  int scol = (lane & 7) << 3;

  auto stage = [&](int buf, int k0) {
#pragma unroll
    for (int p = 0; p < 4; ++p) {
      int cc = (wid << 2) + p;
      int row = (cc << 3) + srow;
      int gc = scol ^ ((row & 7) << 3);
      gload16(A + (size_t)(m0 + row) * K + k0 + gc, &lA[buf][cc << 9]);
    }
#pragma unroll
    for (int p = 0; p < 2; ++p) {
      int cc = (wid << 1) + p;
      int row = (cc << 3) + srow;
      int gc = scol ^ ((row & 7) << 3);
      gload16(Bt + (size_t)(n0 + row) * K + k0 + gc, &lB[buf][cc << 9]);
    }
  };

  int nit = K >> 6;
  stage(0, 0);
  __syncthreads();
  int cur = 0;
  for (int t = 0; t < nit; ++t) {
    if (t + 1 < nit) stage(cur ^ 1, (t + 1) << 6);
#pragma unroll
    for (int kk = 0; kk < 2; ++kk) {
      int kc = kk * 32 + (lg << 3);
      f16x8 af[4], bf[2];
#pragma unroll
      for (int mt = 0; mt < 4; ++mt) {
        int row = wm * 64 + mt * 16 + lr;
        af[mt] = *(const f16x8*)&lA[cur][((row << 6) + kc) ^ ((row & 7) << 3)];
      }
#pragma unroll
      for (int nt = 0; nt < 2; ++nt) {
        int row = wn * 32 + nt * 16 + lr;
        bf[nt] = *(const f16x8*)&lB[cur][((row << 6) + kc) ^ ((row & 7) << 3)];
      }
#pragma unroll
      for (int mt = 0; mt < 4; ++mt)
#pragma unroll
        for (int nt = 0; nt < 2; ++nt)
          acc[mt][nt] = MFMA16(af[mt], bf[nt], acc[mt][nt]);
    }
    if (t + 1 < nit) {
      __syncthreads();
      cur ^= 1;
    }
  }

#pragma unroll
  for (int mt = 0; mt < 4; ++mt) {
#pragma unroll
    for (int nt = 0; nt < 2; ++nt) {
      int row = m0 + wm * 64 + mt * 16 + (lg << 2);
      int col = n0 + wn * 32 + nt * 16 + lr;
      float bv = bias[col];
#pragma unroll
      for (int i = 0; i < 4; ++i)
        out[(size_t)(row + i) * N + col] = acc[mt][nt][i] + bv;
    }
  }
}

// ---------------- sliding-window flash attention (R24/R27 + T13 THR=8) --------
// T13 defer-max: skip rescale unless some row's max grew by >8; P then
// bounded by 2^8 (f16-safe), scaling stays consistent at exp2(-m_old).
// First live tile always triggers (tm >> NEGF+8) -> fac=0 heal preserved.
__global__ __launch_bounds__(256) void attn_kernel(const f16* __restrict__ qn,
                                                   const f16* __restrict__ kn,
                                                   const f16* __restrict__ Vt,
                                                   f16* __restrict__ aout) {
  int sw = ((blockIdx.x & 7) << 7) + (blockIdx.x >> 3);
  int q0 = (sw & 31) << 6;
  int bh = sw >> 5;
  int b = bh >> 4, h = bh & 15;
  int tid = threadIdx.x;
  int w = tid >> 6, lane = tid & 63;
  int lr = lane & 15, lg = lane >> 4;

  __shared__ f16 lK[2][4096];
  __shared__ f16 lV[2][4096];
  __shared__ f16 lP[4096];

  const f16* Qb = qn + (size_t)(b * T + q0 + w * 16 + lr) * E + h * 64 + (lg << 3);
  f16x8 qf0 = *(const f16x8*)Qb;
  f16x8 qf1 = *(const f16x8*)(Qb + 32);

  f32x4 zero = {0.f, 0.f, 0.f, 0.f};
  f32x4 acc[4] = {zero, zero, zero, zero};
  float m[4] = {NEGF, NEGF, NEGF, NEGF};
  float l[4] = {0.f, 0.f, 0.f, 0.f};

  int mi = q0 >> 6;
  int kts = mi - 4 < 0 ? 0 : mi - 4;

  const f16* Kbase = kn + (size_t)b * T * E + h * 64;
  const f16* Vbase = Vt + (size_t)bh * D * T;

  int srow = lane >> 3;
  int scol = (lane & 7) << 3;

  auto stageKV = [&](int buf, int kt) {
    int k0 = kt << 6;
#pragma unroll
    for (int p = 0; p < 2; ++p) {
      int cc = (w << 1) + p;
      int row = (cc << 3) + srow;
      int gc = scol ^ ((row & 7) << 3);
      gload16(Kbase + (size_t)(k0 + row) * E + gc, &lK[buf][cc << 9]);
      gload16(Vbase + (size_t)row * T + k0 + gc, &lV[buf][cc << 9]);
    }
  };

  stageKV(0, kts);
  __syncthreads();
  int cur = 0;

  for (int kt = kts; kt <= mi; ++kt) {
    if (kt < mi) stageKV(cur ^ 1, kt + 1);
    int k0 = kt << 6;

    f32x4 s[4];
#pragma unroll
    for (int ct = 0; ct < 4; ++ct) s[ct] = zero;
    __builtin_amdgcn_s_setprio(1);
#pragma unroll
    for (int kk = 0; kk < 2; ++kk) {
      int kc = kk * 32 + (lg << 3);
#pragma unroll
      for (int ct = 0; ct < 4; ++ct) {
        int row = ct * 16 + lr;
        f16x8 bf = *(const f16x8*)&lK[cur][((row << 6) + kc) ^ ((row & 7) << 3)];
        s[ct] = MFMA16(kk == 0 ? qf0 : qf1, bf, s[ct]);
      }
    }
    __builtin_amdgcn_s_setprio(0);

    float tm[4] = {NEGF, NEGF, NEGF, NEGF};
    int rowg0 = q0 + w * 16 + (lg << 2);
    bool needmask = (kt == mi) || (mi >= 4 && kt == kts);
    if (needmask) {
#pragma unroll
      for (int ct = 0; ct < 4; ++ct) {
        int col = k0 + ct * 16 + lr;
#pragma unroll
        for (int i = 0; i < 4; ++i) {
          int rowg = rowg0 + i;
          float v = s[ct][i];
          if (col > rowg || rowg - col >= WIN) v = NEGF;
          s[ct][i] = v;
          tm[i] = fmaxf(tm[i], v);
        }
      }
    } else {
#pragma unroll
      for (int ct = 0; ct < 4; ++ct)
#pragma unroll
        for (int i = 0; i < 4; ++i) tm[i] = fmaxf(tm[i], s[ct][i]);
    }
#pragma unroll
    for (int i = 0; i < 4; ++i) {
      tm[i] = fmaxf(tm[i], __shfl_xor(tm[i], 1));
      tm[i] = fmaxf(tm[i], __shfl_xor(tm[i], 2));
      tm[i] = fmaxf(tm[i], __shfl_xor(tm[i], 4));
      tm[i] = fmaxf(tm[i], __shfl_xor(tm[i], 8));
    }
    // T13 defer-max (THR=8): rescale only when a row's max grew by >8.
    bool up = (tm[0] > m[0] + 8.0f) || (tm[1] > m[1] + 8.0f) ||
              (tm[2] > m[2] + 8.0f) || (tm[3] > m[3] + 8.0f);
    if (__any(up)) {
      float fac[4];
#pragma unroll
      for (int i = 0; i < 4; ++i) {
        float mn = fmaxf(m[i], tm[i]);
        fac[i] = exp2f((m[i] - mn) * L2E);
        m[i] = mn;
        l[i] *= fac[i];
      }
#pragma unroll
      for (int dt = 0; dt < 4; ++dt)
#pragma unroll
        for (int i = 0; i < 4; ++i) acc[dt][i] *= fac[i];
    }
    float ps[4] = {0.f, 0.f, 0.f, 0.f};
#pragma unroll
    for (int ct = 0; ct < 4; ++ct)
#pragma unroll
      for (int i = 0; i < 4; ++i) {
        float p = exp2f((s[ct][i] - m[i]) * L2E);
        s[ct][i] = p;
        ps[i] += p;
      }
#pragma unroll
    for (int i = 0; i < 4; ++i) {
      ps[i] += __shfl_xor(ps[i], 1);
      ps[i] += __shfl_xor(ps[i], 2);
      ps[i] += __shfl_xor(ps[i], 4);
      ps[i] += __shfl_xor(ps[i], 8);
      l[i] += ps[i];
    }

#pragma unroll
    for (int ct = 0; ct < 4; ++ct)
#pragma unroll
      for (int i = 0; i < 4; ++i) {
        int qloc = (lg << 2) + i;
        int el = (qloc << 6) + ct * 16 + lr;
        lP[w * 1024 + (el ^ ((qloc & 7) << 3))] = (f16)s[ct][i];
      }

    __builtin_amdgcn_s_setprio(1);
#pragma unroll
    for (int kk = 0; kk < 2; ++kk) {
      int kc = kk * 32 + (lg << 3);
      int ep = w * 1024 + (((lr << 6) + kc) ^ ((lr & 7) << 3));
      f16x8 pf = *(const f16x8*)&lP[ep];
#pragma unroll
      for (int dt = 0; dt < 4; ++dt) {
        int row = dt * 16 + lr;
        f16x8 vf = *(const f16x8*)&lV[cur][((row << 6) + kc) ^ ((row & 7) << 3)];
        acc[dt] = MFMA16(pf, vf, acc[dt]);
      }
    }
    __builtin_amdgcn_s_setprio(0);

    if (kt < mi) {
      __syncthreads();
      cur ^= 1;
    }
  }

#pragma unroll
  for (int i = 0; i < 4; ++i) {
    float inv = 1.0f / l[i];
    int tok = q0 + w * 16 + (lg << 2) + i;
    f16* dst = aout + (size_t)(b * T + tok) * E + h * 64 + lr;
#pragma unroll
    for (int dt = 0; dt < 4; ++dt) dst[dt * 16] = (f16)(acc[dt][i] * inv);
  }
}

// ---------------- launch ----------------
extern "C" void kernel_launch(void* const* d_in, const int* in_sizes, int n_in,
                              void* d_out, int out_size, void* d_ws,
                              size_t ws_size, hipStream_t stream) {
  const float* x = (const float*)d_in[0];
  const float* wq = (const float*)d_in[1];
  const float* bq = (const float*)d_in[2];
  const float* wk = (const float*)d_in[3];
  const float* bk = (const float*)d_in[4];
  const float* wv = (const float*)d_in[5];
  const float* bv = (const float*)d_in[6];
  const float* wo = (const float*)d_in[7];
  const float* bo = (const float*)d_in[8];
  const float* qn_w = (const float*)d_in[9];
  const float* kn_w = (const float*)d_in[10];
  float* out = (float*)d_out;

  char* ws = (char*)d_ws;
  const size_t MB = 1u << 20;
  f16* xb = (f16*)(ws);              // 8 MB
  f16* wqT = (f16*)(ws + 8 * MB);    // 2 MB
  f16* wkT = (f16*)(ws + 10 * MB);   // 2 MB
  f16* wvT = (f16*)(ws + 12 * MB);   // 2 MB
  f16* woT = (f16*)(ws + 14 * MB);   // 2 MB
  f16* qn = (f16*)(ws + 16 * MB);    // 8 MB
  f16* kn = (f16*)(ws + 24 * MB);    // 8 MB
  f16* Vt = (f16*)(ws + 32 * MB);    // 8 MB
  f16* aout = (f16*)(ws + 40 * MB);  // 8 MB

  prep_kernel<<<5120, 256, 0, stream>>>(x, xb, wq, wk, wv, wo, wqT, wkT, wvT,
                                        woT);
  qkv_gemm_kernel<<<dim3(512, 1, 3), 256, 0, stream>>>(
      xb, wqT, wkT, wvT, bq, bk, bv, qn_w, kn_w, qn, kn, Vt, 4096, 1024, 1024);
  attn_kernel<<<1024, 256, 0, stream>>>(qn, kn, Vt, aout);
  out_gemm_kernel<<<512, 256, 0, stream>>>(aout, woT, bo, out, 4096, 1024,
                                           1024);
}